// Round 18
// baseline (71.209 us; speedup 1.0000x reference)
//
#include <hip/hip_runtime.h>

#define MODS 4
#define CH   128
#define NHD  4
#define HDIM 32
#define NTOK 1728
#define NKEY (MODS*NTOK)        // 6912
#define NT   27                 // 32-key tiles per 864-key segment
// Q is pre-scaled by 1/sqrt(32) * log2(e); folded into Wq in-register.
#define QSC (0.17677669529663687f * 1.4426950408889634f)

#ifndef __has_builtin
#define __has_builtin(x) 0
#endif
#if __has_builtin(__builtin_amdgcn_exp2f)
#define EXP2(x) __builtin_amdgcn_exp2f(x)
#else
#define EXP2(x) __expf(0.69314718055994531f * (x))
#endif

typedef __bf16 bf16x8 __attribute__((ext_vector_type(8)));
typedef float  f32x16 __attribute__((ext_vector_type(16)));
typedef unsigned int u32x4 __attribute__((ext_vector_type(4)));

__device__ inline bf16x8 ldb8(const unsigned short* p) {
    return *reinterpret_cast<const bf16x8*>(p);
}
__device__ inline unsigned short bfc(float x) {
    return __builtin_bit_cast(unsigned short, (__bf16)x);
}
__device__ inline unsigned int pkbf(float a, float b) {
    return (unsigned int)bfc(a) | ((unsigned int)bfc(b) << 16);
}
// 8 consecutive fp32 -> bf16x8 fragment (optional scale), in-register
__device__ inline bf16x8 cvt8(const float* p, float sc) {
    float4 x = *reinterpret_cast<const float4*>(p);
    float4 y = *reinterpret_cast<const float4*>(p + 4);
    u32x4 u = {pkbf(x.x * sc, x.y * sc), pkbf(x.z * sc, x.w * sc),
               pkbf(y.x * sc, y.y * sc), pkbf(y.z * sc, y.w * sc)};
    return __builtin_bit_cast(bf16x8, u);
}
// async global->LDS, 16B per lane; LDS dest = uniform base + lane*16
__device__ inline void glds16(const unsigned short* g, unsigned short* l) {
    __builtin_amdgcn_global_load_lds(
        (const __attribute__((address_space(1))) unsigned int*)(g),
        (__attribute__((address_space(3))) unsigned int*)(l), 16, 0, 0);
}

// ---------------------------------------------------------------------------
// Kernel 1: fused transpose + MFMA QKV projection (R15 version — best
// measured; 648 blocks = 2.5/CU beats R17's 216-block fusion).
// ---------------------------------------------------------------------------
__global__ __launch_bounds__(256) void proj_kernel(
    const float* __restrict__ f0, const float* __restrict__ f1,
    const float* __restrict__ f2, const float* __restrict__ f3,
    const float* __restrict__ Wq, const float* __restrict__ Wk,
    const float* __restrict__ Wv,
    unsigned short* __restrict__ Qb, unsigned short* __restrict__ Kb,
    unsigned short* __restrict__ V2)
{
    __shared__ __align__(16) unsigned short fT[32][136];  // 8.7 KB
    __shared__ __align__(16) float accf[128 * 33];        // 16.9 KB

    const int tid = threadIdx.x;
    const int lane = tid & 63;
    const int w    = tid >> 6;          // o-tile 0..3
    const int l31  = lane & 31;
    const int hi   = lane >> 5;

    const int bid = blockIdx.x;
    const int tm  = bid / 54;           // 0..11
    const int nb  = (bid % 54) * 32;
    const int t   = tm >> 2, m = tm & 3;

    const float* fsrc = (m == 0) ? f0 : (m == 1) ? f1 : (m == 2) ? f2 : f3;
    const float* Wsrc = ((t == 0) ? Wq : (t == 1) ? Wk : Wv) + (size_t)m * CH * CH;
    const float  wsc  = (t == 0) ? QSC : 1.0f;

    // --- phase 1: build B tile fT[n][c] bf16 ---
    {
        const int n = tid & 31, cg = tid >> 5;       // cg 0..7 (16 c each)
        float v[16];
        #pragma unroll
        for (int k = 0; k < 16; ++k)
            v[k] = fsrc[(size_t)(cg * 16 + k) * NTOK + nb + n];
        unsigned int* dst = reinterpret_cast<unsigned int*>(&fT[n][cg * 16]);
        #pragma unroll
        for (int j = 0; j < 8; ++j) dst[j] = pkbf(v[2 * j], v[2 * j + 1]);
    }
    __syncthreads();

    // --- phase 2: MFMA (A converted in-register from fp32 W) ---
    const float* Wrow = Wsrc + (size_t)(w * 32 + l31) * CH + hi * 8;
    f32x16 acc;
    #pragma unroll
    for (int r = 0; r < 16; ++r) acc[r] = 0.f;
    #pragma unroll
    for (int cc = 0; cc < 8; ++cc) {
        bf16x8 a = cvt8(Wrow + cc * 16, wsc);
        bf16x8 b = ldb8(&fT[l31][cc * 16 + hi * 8]);
        acc = __builtin_amdgcn_mfma_f32_32x32x16_bf16(a, b, acc, 0, 0, 0);
    }
    #pragma unroll
    for (int r = 0; r < 16; ++r) {
        const int orow = w * 32 + (r & 3) + 8 * (r >> 2) + 4 * hi;
        accf[orow * 33 + l31] = acc[r];
    }
    __syncthreads();

    if (t < 2) {
        unsigned short* dstb = (t == 0) ? Qb : Kb;
        const int nl = tid >> 3, dp = (tid & 7) * 4;
        #pragma unroll
        for (int h = 0; h < 4; ++h) {
            ushort4 pk;
            pk.x = bfc(accf[(h * 32 + dp + 0) * 33 + nl]);
            pk.y = bfc(accf[(h * 32 + dp + 1) * 33 + nl]);
            pk.z = bfc(accf[(h * 32 + dp + 2) * 33 + nl]);
            pk.w = bfc(accf[(h * 32 + dp + 3) * 33 + nl]);
            *reinterpret_cast<ushort4*>(
                dstb + (((size_t)(m * NHD + h)) * NTOK + nb + nl) * HDIM + dp) = pk;
        }
    } else {
        const int row = tid >> 1, half = tid & 1;
        const int nw = half * 16;
        unsigned short* dst = V2 + (size_t)row * NKEY + (size_t)m * NTOK + nb + nw;
        const float* src = &accf[row * 33 + nw];
        ushort4 p0, p1, p2, p3;
        p0.x = bfc(src[0]);  p0.y = bfc(src[1]);  p0.z = bfc(src[2]);  p0.w = bfc(src[3]);
        p1.x = bfc(src[8]);  p1.y = bfc(src[9]);  p1.z = bfc(src[10]); p1.w = bfc(src[11]);
        p2.x = bfc(src[4]);  p2.y = bfc(src[5]);  p2.z = bfc(src[6]);  p2.w = bfc(src[7]);
        p3.x = bfc(src[12]); p3.y = bfc(src[13]); p3.z = bfc(src[14]); p3.w = bfc(src[15]);
        *reinterpret_cast<ushort4*>(dst + 0)  = p0;
        *reinterpret_cast<ushort4*>(dst + 4)  = p1;
        *reinterpret_cast<ushort4*>(dst + 8)  = p2;
        *reinterpret_cast<ushort4*>(dst + 12) = p3;
    }
}

// ---------------------------------------------------------------------------
// Kernel 2: MFMA cross-modal attention — BARRIER-FREE main loop.
// Same decomposition as R13 (1728 blocks x 4 waves; slot=bid&7 -> (h,ko);
// qb=rest%108, kseg=rest/108; wave = (qslot, ks)), but each wave stages its
// OWN full 32-key K tile + 32-d V tile (4 glds/tile, private LDS quadrant)
// -> tile readiness is a per-wave vmcnt fact, no cross-wave rendezvous.
// Per tile: vmcnt(4) [own loads, 2-deep] -> 4 ds_reads -> lgkmcnt(0)
// [reads retired] -> STAGE t+2 into just-read buffer -> register compute.
// Swizzle invariance: rows+16 leave both XORs unchanged ((r+16)>>1 ≡ r>>1
// mod 4; (d+16)&3 = d&3) so gkB=gkA+512, gvB=gvA+16*NKEY; read offsets
// byte-identical to R13. LDS 32 KB -> 5 blocks/CU. One __syncthreads after
// the loop re-converges waves for the (unchanged) epilogue.
// ---------------------------------------------------------------------------
__global__ __launch_bounds__(256, 5) void attn_kernel(
    const unsigned short* __restrict__ Qb, const unsigned short* __restrict__ Kb,
    const unsigned short* __restrict__ V2,
    float* __restrict__ accT, float* __restrict__ sR)
{
    __shared__ __align__(16) unsigned short smAll[2][4][2][1024]; // [buf][wave][K/V] 32 KB

    const int tid  = threadIdx.x;
    const int lane = tid & 63;
    const int w    = tid >> 6;        // 0..3
    const int qslot = w & 1;
    const int ks    = w >> 1;
    const int l31  = lane & 31;
    const int hi   = lane >> 5;

    const int bid  = blockIdx.x;
    const int slot = bid & 7;              // XCD slot
    const int h    = slot >> 1;
    const int ko   = slot & 1;
    const int rest = bid >> 3;             // 0..215
    const int qb   = rest % 108;
    const int kseg = rest / 108;           // 0..1
    const int qtile = qb * 2 + qslot;      // 0..215
    const int qg0  = qtile * 32;
    const int im   = qg0 / NTOK;
    const int n0   = qg0 % NTOK;
    const int km   = ko * 2 + ks;
    const int p    = kseg * 2 + ko;        // partial slot 0..3

    const unsigned short* qp = Qb + (((size_t)(im * NHD + h)) * NTOK + n0 + l31) * HDIM + hi * 8;
    const bf16x8 qf0 = ldb8(qp);
    const bf16x8 qf1 = ldb8(qp + 16);

    // --- private staging sources: full tile per wave (rows 0-15 / 16-31) ---
    const int rkh = lane >> 2;                         // 0..15
    const int ckk = (lane & 3) ^ ((rkh >> 1) & 3);     // K chunk swizzle
    const unsigned short* gkA = Kb
        + (((size_t)(km * NHD + h)) * NTOK + kseg * 864 + rkh) * HDIM + ckk * 8;
    const unsigned short* gkB = gkA + 16 * HDIM;       // rows +16 (swizzle invariant)
    const int dvh = lane >> 2;                         // 0..15
    const int cvv = (lane & 3) ^ (dvh & 3);            // V chunk swizzle
    const unsigned short* gvA = V2
        + ((size_t)(h * HDIM + dvh)) * NKEY + km * NTOK + kseg * 864 + cvv * 8;
    const unsigned short* gvB = gvA + (size_t)16 * NKEY;  // d +16 (swizzle invariant)

    // --- LDS read offsets (byte-identical to R13) ---
    const int fK = (l31 >> 1) & 3, fV = l31 & 3;
    const int kA0 = l31 * 32 + ((hi ^ fK) << 3);
    const int kB0 = l31 * 32 + (((2 + hi) ^ fK) << 3);
    const int vo0 = l31 * 32 + ((hi ^ fV) << 3);
    const int vo1 = l31 * 32 + (((2 + hi) ^ fV) << 3);

    f32x16 z;
    #pragma unroll
    for (int r = 0; r < 16; ++r) z[r] = 0.f;
    f32x16 o_acc = z, s_acc = z;
    bf16x8 onesv;
    #pragma unroll
    for (int j = 0; j < 8; ++j) onesv[j] = (__bf16)1.0f;

    // stage one full tile into buffer bb (4 glds; pointers advance)
    #define STAGE(bb) do {                                      \
        unsigned short* _k = &smAll[bb][w][0][0];               \
        glds16(gkA, _k);        glds16(gkB, _k + 512);          \
        unsigned short* _v = &smAll[bb][w][1][0];               \
        glds16(gvA, _v);        glds16(gvB, _v + 512);          \
        gkA += 1024; gkB += 1024; gvA += 32; gvB += 32;         \
    } while (0)

    STAGE(0);                 // tile 0
    STAGE(1);                 // tile 1  (8 outstanding)

    int buf = 0;
    for (int t = 0; t < NT; ++t) {
        // own tile-t loads done (oldest 4 of 8); no cross-wave rendezvous
        if (t < NT - 1) asm volatile("s_waitcnt vmcnt(4)" ::: "memory");
        else            asm volatile("s_waitcnt vmcnt(0)" ::: "memory");

        const unsigned short* Kl = &smAll[buf][w][0][0];
        const unsigned short* Vl = &smAll[buf][w][1][0];
        bf16x8 k0 = ldb8(Kl + kA0);
        bf16x8 k1 = ldb8(Kl + kB0);
        bf16x8 v0 = ldb8(Vl + vo0);
        bf16x8 v1 = ldb8(Vl + vo1);
        // reads retired -> safe to overwrite this buffer with tile t+2
        asm volatile("s_waitcnt lgkmcnt(0)" ::: "memory");
        if (t + 2 < NT) STAGE(buf);

        f32x16 c = __builtin_amdgcn_mfma_f32_32x32x16_bf16(k0, qf0, z, 0, 0, 0);
        c = __builtin_amdgcn_mfma_f32_32x32x16_bf16(k1, qf1, c, 0, 0, 0);

        float e[16];
        #pragma unroll
        for (int r = 0; r < 16; ++r) e[r] = EXP2(c[r]);
        bf16x8 pa0, pa1;
        #pragma unroll
        for (int j = 0; j < 8; ++j) { pa0[j] = (__bf16)e[j]; pa1[j] = (__bf16)e[8 + j]; }

        o_acc = __builtin_amdgcn_mfma_f32_32x32x16_bf16(pa0, v0, o_acc, 0, 0, 0);
        o_acc = __builtin_amdgcn_mfma_f32_32x32x16_bf16(pa1, v1, o_acc, 0, 0, 0);
        s_acc = __builtin_amdgcn_mfma_f32_32x32x16_bf16(pa0, onesv, s_acc, 0, 0, 0);
        s_acc = __builtin_amdgcn_mfma_f32_32x32x16_bf16(pa1, onesv, s_acc, 0, 0, 0);

        buf ^= 1;
    }
    #undef STAGE

    __syncthreads();   // re-converge waves; all glds drained (vmcnt(0) @ last t)

    // --- epilogue: combine ks pair in LDS [64 q][33] (s in col 32) ---
    float* accfL = (float*)&smAll[0][0][0][0];   // 64*33*4 = 8.4 KB (reuse)
    if (ks == 1) {
        #pragma unroll
        for (int r = 0; r < 16; ++r) {
            const int qrow = (r & 3) + 8 * (r >> 2) + 4 * hi;
            accfL[(qslot * 32 + qrow) * 33 + l31] = o_acc[r];
            if (l31 == 0) accfL[(qslot * 32 + qrow) * 33 + 32] = s_acc[r];
        }
    }
    __syncthreads();
    if (ks == 0) {
        #pragma unroll
        for (int r = 0; r < 16; ++r) {
            const int qrow = (r & 3) + 8 * (r >> 2) + 4 * hi;
            accfL[(qslot * 32 + qrow) * 33 + l31] += o_acc[r];
            if (l31 == 0) accfL[(qslot * 32 + qrow) * 33 + 32] += s_acc[r];
        }
    }
    __syncthreads();
    {
        const int q  = tid & 63;
        const int dq = tid >> 6;
        #pragma unroll
        for (int j = 0; j < 8; ++j) {
            const int d = dq * 8 + j;
            accT[((size_t)((p * 4 + h) * HDIM + d)) * NKEY + (size_t)qb * 64 + q]
                = accfL[q * 33 + d];
        }
        if (tid < 64)
            sR[((size_t)(p * 4 + h)) * NKEY + (size_t)qb * 64 + tid] = accfL[tid * 33 + 32];
    }
}

// ---------------------------------------------------------------------------
// Kernel 3: fused normalize + modality-sum + MFMA out-proj + BN + ReLU
// (R14/R15, kept). 54 blocks × 512 thr.
// ---------------------------------------------------------------------------
__global__ __launch_bounds__(512) void normout_kernel(
    const float* __restrict__ accT, const float* __restrict__ sR,
    const float* __restrict__ Wout,
    const float* __restrict__ gamma, const float* __restrict__ beta,
    const float* __restrict__ mean,  const float* __restrict__ var,
    float* __restrict__ out)
{
    __shared__ __align__(16) unsigned short fT2[32][136];  // 8.7 KB
    __shared__ float rsL[4][4][32];                        // 2 KB

    const int tid = threadIdx.x;
    const int nb  = blockIdx.x * 32;

    // --- phase A: rsL[h][imq][n] = 1 / sum_pp sR ---
    {
        const int h = tid >> 7, imq = (tid >> 5) & 3, n = tid & 31;
        float s = 0.f;
        #pragma unroll
        for (int pp = 0; pp < 4; ++pp)
            s += sR[(size_t)(pp * 4 + h) * NKEY + (size_t)imq * NTOK + nb + n];
        rsL[h][imq][n] = 1.0f / s;
    }
    __syncthreads();

    // --- phase B: fusedT[n][c] bf16 (thread = 2c × 4n) ---
    {
        const int n4 = (tid & 7) * 4;        // n base
        const int c0 = (tid >> 3) * 2;       // c base (even, 0..126)
        const int h  = c0 >> 5;
        float acc4[2][4] = {};
        #pragma unroll
        for (int imq = 0; imq < 4; ++imq) {
            const size_t q = (size_t)imq * NTOK + nb + n4;
            float a[2][4] = {};
            #pragma unroll
            for (int pp = 0; pp < 4; ++pp) {
                #pragma unroll
                for (int cc = 0; cc < 2; ++cc) {
                    const int d = (c0 + cc) & 31;
                    float4 x = *reinterpret_cast<const float4*>(
                        accT + ((size_t)((pp * 4 + h) * HDIM + d)) * NKEY + q);
                    a[cc][0] += x.x; a[cc][1] += x.y; a[cc][2] += x.z; a[cc][3] += x.w;
                }
            }
            #pragma unroll
            for (int cc = 0; cc < 2; ++cc)
                #pragma unroll
                for (int nn = 0; nn < 4; ++nn)
                    acc4[cc][nn] = fmaf(a[cc][nn], rsL[h][imq][n4 + nn], acc4[cc][nn]);
        }
        #pragma unroll
        for (int nn = 0; nn < 4; ++nn) {
            ushort2 pk;
            pk.x = bfc(acc4[0][nn]); pk.y = bfc(acc4[1][nn]);
            *reinterpret_cast<ushort2*>(&fT2[n4 + nn][c0]) = pk;
        }
    }
    __syncthreads();

    // --- phase C: MFMA out-proj + BN + ReLU (waves 0-3) ---
    if (tid < 256) {
        const int lane = tid & 63;
        const int w    = tid >> 6;
        const int l31  = lane & 31;
        const int hi   = lane >> 5;
        const float* Arow = Wout + (size_t)(w * 32 + l31) * CH + hi * 8;
        f32x16 acc;
        #pragma unroll
        for (int r = 0; r < 16; ++r) acc[r] = 0.f;
        #pragma unroll
        for (int cc = 0; cc < 8; ++cc) {
            bf16x8 a = cvt8(Arow + cc * 16, 1.0f);
            bf16x8 b = ldb8(&fT2[l31][cc * 16 + hi * 8]);
            acc = __builtin_amdgcn_mfma_f32_32x32x16_bf16(a, b, acc, 0, 0, 0);
        }
        #pragma unroll
        for (int r = 0; r < 16; ++r) {
            const int orow = w * 32 + (r & 3) + 8 * (r >> 2) + 4 * hi;
            const float inv = gamma[orow] * rsqrtf(var[orow] + 1e-5f);
            const float sh  = fmaf(-mean[orow], inv, beta[orow]);
            out[(size_t)orow * NTOK + nb + l31] = fmaxf(fmaf(acc[r], inv, sh), 0.f);
        }
    }
}

// ---------------------------------------------------------------------------
extern "C" void kernel_launch(void* const* d_in, const int* in_sizes, int n_in,
                              void* d_out, int out_size, void* d_ws, size_t ws_size,
                              hipStream_t stream)
{
    const float* f0    = (const float*)d_in[0];
    const float* f1    = (const float*)d_in[1];
    const float* f2    = (const float*)d_in[2];
    const float* f3    = (const float*)d_in[3];
    const float* Wq    = (const float*)d_in[4];
    const float* Wk    = (const float*)d_in[5];
    const float* Wv    = (const float*)d_in[6];
    const float* Wout  = (const float*)d_in[7];
    const float* gamma = (const float*)d_in[8];
    const float* beta  = (const float*)d_in[9];
    const float* mean  = (const float*)d_in[10];
    const float* var   = (const float*)d_in[11];
    float* out = (float*)d_out;

    const size_t QKV = (size_t)MODS * NHD * NTOK * HDIM;   // 884736 elems
    unsigned short* Qb  = (unsigned short*)d_ws;
    unsigned short* Kb  = Qb + QKV;
    unsigned short* V2  = Kb + QKV;
    float* accT = (float*)(V2 + QKV);           // [512 rows][6912 q] f32
    float* sR   = accT + (size_t)512 * NKEY;    // [16][6912] f32

    proj_kernel<<<648, 256, 0, stream>>>(f0, f1, f2, f3, Wq, Wk, Wv, Qb, Kb, V2);
    attn_kernel<<<1728, 256, 0, stream>>>(Qb, Kb, V2, accT, sR);
    normout_kernel<<<54, 512, 0, stream>>>(
        accT, sR, Wout, gamma, beta, mean, var, out);
}

// Round 19
// 65.845 us; speedup vs baseline: 1.0815x; 1.0815x over previous
//
#include <hip/hip_runtime.h>

#define MODS 4
#define CH   128
#define NHD  4
#define HDIM 32
#define NTOK 1728
#define NKEY (MODS*NTOK)        // 6912
#define NT   27                 // 32-key tiles per 864-key segment
// Q is pre-scaled by 1/sqrt(32) * log2(e); folded into Wq in-register.
#define QSC (0.17677669529663687f * 1.4426950408889634f)

#ifndef __has_builtin
#define __has_builtin(x) 0
#endif
#if __has_builtin(__builtin_amdgcn_exp2f)
#define EXP2(x) __builtin_amdgcn_exp2f(x)
#else
#define EXP2(x) __expf(0.69314718055994531f * (x))
#endif

typedef __bf16 bf16x8 __attribute__((ext_vector_type(8)));
typedef float  f32x16 __attribute__((ext_vector_type(16)));
typedef unsigned int u32x4 __attribute__((ext_vector_type(4)));

__device__ inline bf16x8 ldb8(const unsigned short* p) {
    return *reinterpret_cast<const bf16x8*>(p);
}
__device__ inline unsigned short bfc(float x) {
    return __builtin_bit_cast(unsigned short, (__bf16)x);
}
__device__ inline unsigned int pkbf(float a, float b) {
    return (unsigned int)bfc(a) | ((unsigned int)bfc(b) << 16);
}
// 8 consecutive fp32 -> bf16x8 fragment (optional scale), in-register
__device__ inline bf16x8 cvt8(const float* p, float sc) {
    float4 x = *reinterpret_cast<const float4*>(p);
    float4 y = *reinterpret_cast<const float4*>(p + 4);
    u32x4 u = {pkbf(x.x * sc, x.y * sc), pkbf(x.z * sc, x.w * sc),
               pkbf(y.x * sc, y.y * sc), pkbf(y.z * sc, y.w * sc)};
    return __builtin_bit_cast(bf16x8, u);
}
// async global->LDS, 16B per lane; LDS dest = uniform base + lane*16
__device__ inline void glds16(const unsigned short* g, unsigned short* l) {
    __builtin_amdgcn_global_load_lds(
        (const __attribute__((address_space(1))) unsigned int*)(g),
        (__attribute__((address_space(3))) unsigned int*)(l), 16, 0, 0);
}

// ---------------------------------------------------------------------------
// Kernel 1: fused transpose + MFMA QKV projection (R15 — best measured).
// 648 blocks (12tm × 54nt), 256 thr.
// ---------------------------------------------------------------------------
__global__ __launch_bounds__(256) void proj_kernel(
    const float* __restrict__ f0, const float* __restrict__ f1,
    const float* __restrict__ f2, const float* __restrict__ f3,
    const float* __restrict__ Wq, const float* __restrict__ Wk,
    const float* __restrict__ Wv,
    unsigned short* __restrict__ Qb, unsigned short* __restrict__ Kb,
    unsigned short* __restrict__ V2)
{
    __shared__ __align__(16) unsigned short fT[32][136];  // 8.7 KB
    __shared__ __align__(16) float accf[128 * 33];        // 16.9 KB

    const int tid = threadIdx.x;
    const int lane = tid & 63;
    const int w    = tid >> 6;          // o-tile 0..3
    const int l31  = lane & 31;
    const int hi   = lane >> 5;

    const int bid = blockIdx.x;
    const int tm  = bid / 54;           // 0..11
    const int nb  = (bid % 54) * 32;
    const int t   = tm >> 2, m = tm & 3;

    const float* fsrc = (m == 0) ? f0 : (m == 1) ? f1 : (m == 2) ? f2 : f3;
    const float* Wsrc = ((t == 0) ? Wq : (t == 1) ? Wk : Wv) + (size_t)m * CH * CH;
    const float  wsc  = (t == 0) ? QSC : 1.0f;

    // --- phase 1: build B tile fT[n][c] bf16 ---
    {
        const int n = tid & 31, cg = tid >> 5;       // cg 0..7 (16 c each)
        float v[16];
        #pragma unroll
        for (int k = 0; k < 16; ++k)
            v[k] = fsrc[(size_t)(cg * 16 + k) * NTOK + nb + n];
        unsigned int* dst = reinterpret_cast<unsigned int*>(&fT[n][cg * 16]);
        #pragma unroll
        for (int j = 0; j < 8; ++j) dst[j] = pkbf(v[2 * j], v[2 * j + 1]);
    }
    __syncthreads();

    // --- phase 2: MFMA (A converted in-register from fp32 W) ---
    const float* Wrow = Wsrc + (size_t)(w * 32 + l31) * CH + hi * 8;
    f32x16 acc;
    #pragma unroll
    for (int r = 0; r < 16; ++r) acc[r] = 0.f;
    #pragma unroll
    for (int cc = 0; cc < 8; ++cc) {
        bf16x8 a = cvt8(Wrow + cc * 16, wsc);
        bf16x8 b = ldb8(&fT[l31][cc * 16 + hi * 8]);
        acc = __builtin_amdgcn_mfma_f32_32x32x16_bf16(a, b, acc, 0, 0, 0);
    }
    #pragma unroll
    for (int r = 0; r < 16; ++r) {
        const int orow = w * 32 + (r & 3) + 8 * (r >> 2) + 4 * hi;
        accf[orow * 33 + l31] = acc[r];
    }
    __syncthreads();

    if (t < 2) {
        unsigned short* dstb = (t == 0) ? Qb : Kb;
        const int nl = tid >> 3, dp = (tid & 7) * 4;
        #pragma unroll
        for (int h = 0; h < 4; ++h) {
            ushort4 pk;
            pk.x = bfc(accf[(h * 32 + dp + 0) * 33 + nl]);
            pk.y = bfc(accf[(h * 32 + dp + 1) * 33 + nl]);
            pk.z = bfc(accf[(h * 32 + dp + 2) * 33 + nl]);
            pk.w = bfc(accf[(h * 32 + dp + 3) * 33 + nl]);
            *reinterpret_cast<ushort4*>(
                dstb + (((size_t)(m * NHD + h)) * NTOK + nb + nl) * HDIM + dp) = pk;
        }
    } else {
        const int row = tid >> 1, half = tid & 1;
        const int nw = half * 16;
        unsigned short* dst = V2 + (size_t)row * NKEY + (size_t)m * NTOK + nb + nw;
        const float* src = &accf[row * 33 + nw];
        ushort4 p0, p1, p2, p3;
        p0.x = bfc(src[0]);  p0.y = bfc(src[1]);  p0.z = bfc(src[2]);  p0.w = bfc(src[3]);
        p1.x = bfc(src[8]);  p1.y = bfc(src[9]);  p1.z = bfc(src[10]); p1.w = bfc(src[11]);
        p2.x = bfc(src[4]);  p2.y = bfc(src[5]);  p2.z = bfc(src[6]);  p2.w = bfc(src[7]);
        p3.x = bfc(src[12]); p3.y = bfc(src[13]); p3.z = bfc(src[14]); p3.w = bfc(src[15]);
        *reinterpret_cast<ushort4*>(dst + 0)  = p0;
        *reinterpret_cast<ushort4*>(dst + 4)  = p1;
        *reinterpret_cast<ushort4*>(dst + 8)  = p2;
        *reinterpret_cast<ushort4*>(dst + 12) = p3;
    }
}

// ---------------------------------------------------------------------------
// Kernel 2: MFMA cross-modal attention — R13 byte-identical (the 43.8 µs
// configuration; reproduced 5x; all nine schedule deviations regressed).
// 1728 blocks x 4 waves; slot=bid&7 -> (h,ko); qb=rest%108, kseg=rest/108.
// Swizzles (bank-enumerated): K chunk ^= (key>>1)&3, V chunk ^= d&3;
// pre-applied on glds SOURCE, involution on ds_read. ones-B denominator.
// ---------------------------------------------------------------------------
__global__ __launch_bounds__(256, 6) void attn_kernel(
    const unsigned short* __restrict__ Qb, const unsigned short* __restrict__ Kb,
    const unsigned short* __restrict__ V2,
    float* __restrict__ accT, float* __restrict__ sR)
{
    __shared__ __align__(16) unsigned short smAll[2][2][2][1024]; // 16 KB

    const int tid  = threadIdx.x;
    const int lane = tid & 63;
    const int w    = tid >> 6;        // 0..3
    const int qslot = w & 1;
    const int ks    = w >> 1;
    const int l31  = lane & 31;
    const int hi   = lane >> 5;

    const int bid  = blockIdx.x;
    const int slot = bid & 7;              // XCD slot
    const int h    = slot >> 1;
    const int ko   = slot & 1;
    const int rest = bid >> 3;             // 0..215
    const int qb   = rest % 108;
    const int kseg = rest / 108;           // 0..1
    const int qtile = qb * 2 + qslot;      // 0..215
    const int qg0  = qtile * 32;
    const int im   = qg0 / NTOK;
    const int n0   = qg0 % NTOK;
    const int km   = ko * 2 + ks;
    const int p    = kseg * 2 + ko;        // partial slot 0..3

    const unsigned short* qp = Qb + (((size_t)(im * NHD + h)) * NTOK + n0 + l31) * HDIM + hi * 8;
    const bf16x8 qf0 = ldb8(qp);
    const bf16x8 qf1 = ldb8(qp + 16);

    const int rk0 = qslot * 16 + (lane >> 2);
    const int ck0 = (lane & 3) ^ ((rk0 >> 1) & 3);
    const unsigned short* gk0 = Kb
        + (((size_t)(km * NHD + h)) * NTOK + kseg * 864 + rk0) * HDIM + ck0 * 8;
    const int dv0 = qslot * 16 + (lane >> 2);
    const int cv0 = (lane & 3) ^ (dv0 & 3);
    const unsigned short* gv0 = V2
        + ((size_t)(h * HDIM + dv0)) * NKEY + km * NTOK + kseg * 864 + cv0 * 8;

    const int fK = (l31 >> 1) & 3, fV = l31 & 3;
    const int kA0 = l31 * 32 + ((hi ^ fK) << 3);
    const int kB0 = l31 * 32 + (((2 + hi) ^ fK) << 3);
    const int vo0 = l31 * 32 + ((hi ^ fV) << 3);
    const int vo1 = l31 * 32 + (((2 + hi) ^ fV) << 3);

    f32x16 z;
    #pragma unroll
    for (int r = 0; r < 16; ++r) z[r] = 0.f;
    f32x16 o_acc = z, s_acc = z;
    bf16x8 onesv;
    #pragma unroll
    for (int j = 0; j < 8; ++j) onesv[j] = (__bf16)1.0f;

    #define STAGE(bb) do {                                      \
        glds16(gk0, &smAll[bb][ks][0][0] + qslot * 512);        \
        glds16(gv0, &smAll[bb][ks][1][0] + qslot * 512);        \
        gk0 += 1024; gv0 += 32;                                 \
    } while (0)

    STAGE(0);
    __syncthreads();

    int buf = 0;
    for (int t = 0; t < NT; ++t) {
        if (t + 1 < NT) STAGE(buf ^ 1);
        const unsigned short* Kl = &smAll[buf][ks][0][0];
        const unsigned short* Vl = &smAll[buf][ks][1][0];

        bf16x8 k0 = ldb8(Kl + kA0);
        bf16x8 k1 = ldb8(Kl + kB0);
        f32x16 c = __builtin_amdgcn_mfma_f32_32x32x16_bf16(k0, qf0, z, 0, 0, 0);
        c = __builtin_amdgcn_mfma_f32_32x32x16_bf16(k1, qf1, c, 0, 0, 0);

        float e[16];
        #pragma unroll
        for (int r = 0; r < 16; ++r) e[r] = EXP2(c[r]);
        bf16x8 pa0, pa1;
        #pragma unroll
        for (int j = 0; j < 8; ++j) { pa0[j] = (__bf16)e[j]; pa1[j] = (__bf16)e[8 + j]; }

        bf16x8 v0 = ldb8(Vl + vo0);
        bf16x8 v1 = ldb8(Vl + vo1);

        o_acc = __builtin_amdgcn_mfma_f32_32x32x16_bf16(pa0, v0, o_acc, 0, 0, 0);
        o_acc = __builtin_amdgcn_mfma_f32_32x32x16_bf16(pa1, v1, o_acc, 0, 0, 0);
        s_acc = __builtin_amdgcn_mfma_f32_32x32x16_bf16(pa0, onesv, s_acc, 0, 0, 0);
        s_acc = __builtin_amdgcn_mfma_f32_32x32x16_bf16(pa1, onesv, s_acc, 0, 0, 0);

        __syncthreads();
        buf ^= 1;
    }
    #undef STAGE

    float* accfL = (float*)&smAll[0][0][0][0];   // 64*33*4 = 8.4 KB (reuse)
    if (ks == 1) {
        #pragma unroll
        for (int r = 0; r < 16; ++r) {
            const int qrow = (r & 3) + 8 * (r >> 2) + 4 * hi;
            accfL[(qslot * 32 + qrow) * 33 + l31] = o_acc[r];
            if (l31 == 0) accfL[(qslot * 32 + qrow) * 33 + 32] = s_acc[r];
        }
    }
    __syncthreads();
    if (ks == 0) {
        #pragma unroll
        for (int r = 0; r < 16; ++r) {
            const int qrow = (r & 3) + 8 * (r >> 2) + 4 * hi;
            accfL[(qslot * 32 + qrow) * 33 + l31] += o_acc[r];
            if (l31 == 0) accfL[(qslot * 32 + qrow) * 33 + 32] += s_acc[r];
        }
    }
    __syncthreads();
    {
        const int q  = tid & 63;
        const int dq = tid >> 6;
        #pragma unroll
        for (int j = 0; j < 8; ++j) {
            const int d = dq * 8 + j;
            accT[((size_t)((p * 4 + h) * HDIM + d)) * NKEY + (size_t)qb * 64 + q]
                = accfL[q * 33 + d];
        }
        if (tid < 64)
            sR[((size_t)(p * 4 + h)) * NKEY + (size_t)qb * 64 + tid] = accfL[tid * 33 + 32];
    }
}

// ---------------------------------------------------------------------------
// Kernel 3: fused normalize + modality-sum + MFMA out-proj + BN + ReLU
// (R14/R15). 54 blocks × 512 thr.
// ---------------------------------------------------------------------------
__global__ __launch_bounds__(512) void normout_kernel(
    const float* __restrict__ accT, const float* __restrict__ sR,
    const float* __restrict__ Wout,
    const float* __restrict__ gamma, const float* __restrict__ beta,
    const float* __restrict__ mean,  const float* __restrict__ var,
    float* __restrict__ out)
{
    __shared__ __align__(16) unsigned short fT2[32][136];  // 8.7 KB
    __shared__ float rsL[4][4][32];                        // 2 KB

    const int tid = threadIdx.x;
    const int nb  = blockIdx.x * 32;

    // --- phase A: rsL[h][imq][n] = 1 / sum_pp sR ---
    {
        const int h = tid >> 7, imq = (tid >> 5) & 3, n = tid & 31;
        float s = 0.f;
        #pragma unroll
        for (int pp = 0; pp < 4; ++pp)
            s += sR[(size_t)(pp * 4 + h) * NKEY + (size_t)imq * NTOK + nb + n];
        rsL[h][imq][n] = 1.0f / s;
    }
    __syncthreads();

    // --- phase B: fusedT[n][c] bf16 (thread = 2c × 4n) ---
    {
        const int n4 = (tid & 7) * 4;        // n base
        const int c0 = (tid >> 3) * 2;       // c base (even, 0..126)
        const int h  = c0 >> 5;
        float acc4[2][4] = {};
        #pragma unroll
        for (int imq = 0; imq < 4; ++imq) {
            const size_t q = (size_t)imq * NTOK + nb + n4;
            float a[2][4] = {};
            #pragma unroll
            for (int pp = 0; pp < 4; ++pp) {
                #pragma unroll
                for (int cc = 0; cc < 2; ++cc) {
                    const int d = (c0 + cc) & 31;
                    float4 x = *reinterpret_cast<const float4*>(
                        accT + ((size_t)((pp * 4 + h) * HDIM + d)) * NKEY + q);
                    a[cc][0] += x.x; a[cc][1] += x.y; a[cc][2] += x.z; a[cc][3] += x.w;
                }
            }
            #pragma unroll
            for (int cc = 0; cc < 2; ++cc)
                #pragma unroll
                for (int nn = 0; nn < 4; ++nn)
                    acc4[cc][nn] = fmaf(a[cc][nn], rsL[h][imq][n4 + nn], acc4[cc][nn]);
        }
        #pragma unroll
        for (int nn = 0; nn < 4; ++nn) {
            ushort2 pk;
            pk.x = bfc(acc4[0][nn]); pk.y = bfc(acc4[1][nn]);
            *reinterpret_cast<ushort2*>(&fT2[n4 + nn][c0]) = pk;
        }
    }
    __syncthreads();

    // --- phase C: MFMA out-proj + BN + ReLU (waves 0-3) ---
    if (tid < 256) {
        const int lane = tid & 63;
        const int w    = tid >> 6;
        const int l31  = lane & 31;
        const int hi   = lane >> 5;
        const float* Arow = Wout + (size_t)(w * 32 + l31) * CH + hi * 8;
        f32x16 acc;
        #pragma unroll
        for (int r = 0; r < 16; ++r) acc[r] = 0.f;
        #pragma unroll
        for (int cc = 0; cc < 8; ++cc) {
            bf16x8 a = cvt8(Arow + cc * 16, 1.0f);
            bf16x8 b = ldb8(&fT2[l31][cc * 16 + hi * 8]);
            acc = __builtin_amdgcn_mfma_f32_32x32x16_bf16(a, b, acc, 0, 0, 0);
        }
        #pragma unroll
        for (int r = 0; r < 16; ++r) {
            const int orow = w * 32 + (r & 3) + 8 * (r >> 2) + 4 * hi;
            const float inv = gamma[orow] * rsqrtf(var[orow] + 1e-5f);
            const float sh  = fmaf(-mean[orow], inv, beta[orow]);
            out[(size_t)orow * NTOK + nb + l31] = fmaxf(fmaf(acc[r], inv, sh), 0.f);
        }
    }
}

// ---------------------------------------------------------------------------
extern "C" void kernel_launch(void* const* d_in, const int* in_sizes, int n_in,
                              void* d_out, int out_size, void* d_ws, size_t ws_size,
                              hipStream_t stream)
{
    const float* f0    = (const float*)d_in[0];
    const float* f1    = (const float*)d_in[1];
    const float* f2    = (const float*)d_in[2];
    const float* f3    = (const float*)d_in[3];
    const float* Wq    = (const float*)d_in[4];
    const float* Wk    = (const float*)d_in[5];
    const float* Wv    = (const float*)d_in[6];
    const float* Wout  = (const float*)d_in[7];
    const float* gamma = (const float*)d_in[8];
    const float* beta  = (const float*)d_in[9];
    const float* mean  = (const float*)d_in[10];
    const float* var   = (const float*)d_in[11];
    float* out = (float*)d_out;

    const size_t QKV = (size_t)MODS * NHD * NTOK * HDIM;   // 884736 elems
    unsigned short* Qb  = (unsigned short*)d_ws;
    unsigned short* Kb  = Qb + QKV;
    unsigned short* V2  = Kb + QKV;
    float* accT = (float*)(V2 + QKV);           // [512 rows][6912 q] f32
    float* sR   = accT + (size_t)512 * NKEY;    // [16][6912] f32

    proj_kernel<<<648, 256, 0, stream>>>(f0, f1, f2, f3, Wq, Wk, Wv, Qb, Kb, V2);
    attn_kernel<<<1728, 256, 0, stream>>>(Qb, Kb, V2, accT, sR);
    normout_kernel<<<54, 512, 0, stream>>>(
        accT, sR, Wout, gamma, beta, mean, var, out);
}

// Round 20
// 65.429 us; speedup vs baseline: 1.0883x; 1.0064x over previous
//
#include <hip/hip_runtime.h>

#define MODS 4
#define CH   128
#define NHD  4
#define HDIM 32
#define NTOK 1728
#define NKEY (MODS*NTOK)        // 6912
#define NT   27                 // 32-key tiles per 864-key segment
// Q is pre-scaled by 1/sqrt(32) * log2(e); folded into Wq in-register.
#define QSC (0.17677669529663687f * 1.4426950408889634f)

#ifndef __has_builtin
#define __has_builtin(x) 0
#endif
#if __has_builtin(__builtin_amdgcn_exp2f)
#define EXP2(x) __builtin_amdgcn_exp2f(x)
#else
#define EXP2(x) __expf(0.69314718055994531f * (x))
#endif

typedef __bf16 bf16x8 __attribute__((ext_vector_type(8)));
typedef float  f32x16 __attribute__((ext_vector_type(16)));
typedef unsigned int u32x4 __attribute__((ext_vector_type(4)));

__device__ inline bf16x8 ldb8(const unsigned short* p) {
    return *reinterpret_cast<const bf16x8*>(p);
}
__device__ inline unsigned short bfc(float x) {
    return __builtin_bit_cast(unsigned short, (__bf16)x);
}
__device__ inline unsigned int pkbf(float a, float b) {
    return (unsigned int)bfc(a) | ((unsigned int)bfc(b) << 16);
}
// 8 consecutive fp32 -> bf16x8 fragment (optional scale), in-register
__device__ inline bf16x8 cvt8(const float* p, float sc) {
    float4 x = *reinterpret_cast<const float4*>(p);
    float4 y = *reinterpret_cast<const float4*>(p + 4);
    u32x4 u = {pkbf(x.x * sc, x.y * sc), pkbf(x.z * sc, x.w * sc),
               pkbf(y.x * sc, y.y * sc), pkbf(y.z * sc, y.w * sc)};
    return __builtin_bit_cast(bf16x8, u);
}
// async global->LDS, 16B per lane; LDS dest = uniform base + lane*16
__device__ inline void glds16(const unsigned short* g, unsigned short* l) {
    __builtin_amdgcn_global_load_lds(
        (const __attribute__((address_space(1))) unsigned int*)(g),
        (__attribute__((address_space(3))) unsigned int*)(l), 16, 0, 0);
}

// ---------------------------------------------------------------------------
// Kernel 1: fused transpose + MFMA QKV projection (R15 — best measured).
// 648 blocks (12tm × 54nt), 256 thr.
// ---------------------------------------------------------------------------
__global__ __launch_bounds__(256) void proj_kernel(
    const float* __restrict__ f0, const float* __restrict__ f1,
    const float* __restrict__ f2, const float* __restrict__ f3,
    const float* __restrict__ Wq, const float* __restrict__ Wk,
    const float* __restrict__ Wv,
    unsigned short* __restrict__ Qb, unsigned short* __restrict__ Kb,
    unsigned short* __restrict__ V2)
{
    __shared__ __align__(16) unsigned short fT[32][136];  // 8.7 KB
    __shared__ __align__(16) float accf[128 * 33];        // 16.9 KB

    const int tid = threadIdx.x;
    const int lane = tid & 63;
    const int w    = tid >> 6;          // o-tile 0..3
    const int l31  = lane & 31;
    const int hi   = lane >> 5;

    const int bid = blockIdx.x;
    const int tm  = bid / 54;           // 0..11
    const int nb  = (bid % 54) * 32;
    const int t   = tm >> 2, m = tm & 3;

    const float* fsrc = (m == 0) ? f0 : (m == 1) ? f1 : (m == 2) ? f2 : f3;
    const float* Wsrc = ((t == 0) ? Wq : (t == 1) ? Wk : Wv) + (size_t)m * CH * CH;
    const float  wsc  = (t == 0) ? QSC : 1.0f;

    // --- phase 1: build B tile fT[n][c] bf16 ---
    {
        const int n = tid & 31, cg = tid >> 5;       // cg 0..7 (16 c each)
        float v[16];
        #pragma unroll
        for (int k = 0; k < 16; ++k)
            v[k] = fsrc[(size_t)(cg * 16 + k) * NTOK + nb + n];
        unsigned int* dst = reinterpret_cast<unsigned int*>(&fT[n][cg * 16]);
        #pragma unroll
        for (int j = 0; j < 8; ++j) dst[j] = pkbf(v[2 * j], v[2 * j + 1]);
    }
    __syncthreads();

    // --- phase 2: MFMA (A converted in-register from fp32 W) ---
    const float* Wrow = Wsrc + (size_t)(w * 32 + l31) * CH + hi * 8;
    f32x16 acc;
    #pragma unroll
    for (int r = 0; r < 16; ++r) acc[r] = 0.f;
    #pragma unroll
    for (int cc = 0; cc < 8; ++cc) {
        bf16x8 a = cvt8(Wrow + cc * 16, wsc);
        bf16x8 b = ldb8(&fT[l31][cc * 16 + hi * 8]);
        acc = __builtin_amdgcn_mfma_f32_32x32x16_bf16(a, b, acc, 0, 0, 0);
    }
    #pragma unroll
    for (int r = 0; r < 16; ++r) {
        const int orow = w * 32 + (r & 3) + 8 * (r >> 2) + 4 * hi;
        accf[orow * 33 + l31] = acc[r];
    }
    __syncthreads();

    if (t < 2) {
        unsigned short* dstb = (t == 0) ? Qb : Kb;
        const int nl = tid >> 3, dp = (tid & 7) * 4;
        #pragma unroll
        for (int h = 0; h < 4; ++h) {
            ushort4 pk;
            pk.x = bfc(accf[(h * 32 + dp + 0) * 33 + nl]);
            pk.y = bfc(accf[(h * 32 + dp + 1) * 33 + nl]);
            pk.z = bfc(accf[(h * 32 + dp + 2) * 33 + nl]);
            pk.w = bfc(accf[(h * 32 + dp + 3) * 33 + nl]);
            *reinterpret_cast<ushort4*>(
                dstb + (((size_t)(m * NHD + h)) * NTOK + nb + nl) * HDIM + dp) = pk;
        }
    } else {
        const int row = tid >> 1, half = tid & 1;
        const int nw = half * 16;
        unsigned short* dst = V2 + (size_t)row * NKEY + (size_t)m * NTOK + nb + nw;
        const float* src = &accf[row * 33 + nw];
        ushort4 p0, p1, p2, p3;
        p0.x = bfc(src[0]);  p0.y = bfc(src[1]);  p0.z = bfc(src[2]);  p0.w = bfc(src[3]);
        p1.x = bfc(src[8]);  p1.y = bfc(src[9]);  p1.z = bfc(src[10]); p1.w = bfc(src[11]);
        p2.x = bfc(src[4]);  p2.y = bfc(src[5]);  p2.z = bfc(src[6]);  p2.w = bfc(src[7]);
        p3.x = bfc(src[12]); p3.y = bfc(src[13]); p3.z = bfc(src[14]); p3.w = bfc(src[15]);
        *reinterpret_cast<ushort4*>(dst + 0)  = p0;
        *reinterpret_cast<ushort4*>(dst + 4)  = p1;
        *reinterpret_cast<ushort4*>(dst + 8)  = p2;
        *reinterpret_cast<ushort4*>(dst + 12) = p3;
    }
}

// ---------------------------------------------------------------------------
// Kernel 2: MFMA cross-modal attention — R13 structure with FIXED V swizzle.
// The only delta vs the 6x-reproduced R13 kernel: V uses f(d)=(d>>1)&3
// (was d&3). 16-lane-phase enumeration: bank = 16*(l31&1) + 4x mod 32, so
// the XOR field must separate even lanes; old fV=l31&3 collapsed to {0,2}
// -> lanes {0,4,8,12} 4-way (1.58x) = the constant 5.97M conflict counter.
// New fV=(l31>>1)&3 = K's proven pattern -> 2-way = free (m136).
// Store side changed consistently (both-sides rule): cv=(lane&3)^((dv>>1)&3).
// ---------------------------------------------------------------------------
__global__ __launch_bounds__(256, 6) void attn_kernel(
    const unsigned short* __restrict__ Qb, const unsigned short* __restrict__ Kb,
    const unsigned short* __restrict__ V2,
    float* __restrict__ accT, float* __restrict__ sR)
{
    __shared__ __align__(16) unsigned short smAll[2][2][2][1024]; // 16 KB

    const int tid  = threadIdx.x;
    const int lane = tid & 63;
    const int w    = tid >> 6;        // 0..3
    const int qslot = w & 1;
    const int ks    = w >> 1;
    const int l31  = lane & 31;
    const int hi   = lane >> 5;

    const int bid  = blockIdx.x;
    const int slot = bid & 7;              // XCD slot
    const int h    = slot >> 1;
    const int ko   = slot & 1;
    const int rest = bid >> 3;             // 0..215
    const int qb   = rest % 108;
    const int kseg = rest / 108;           // 0..1
    const int qtile = qb * 2 + qslot;      // 0..215
    const int qg0  = qtile * 32;
    const int im   = qg0 / NTOK;
    const int n0   = qg0 % NTOK;
    const int km   = ko * 2 + ks;
    const int p    = kseg * 2 + ko;        // partial slot 0..3

    const unsigned short* qp = Qb + (((size_t)(im * NHD + h)) * NTOK + n0 + l31) * HDIM + hi * 8;
    const bf16x8 qf0 = ldb8(qp);
    const bf16x8 qf1 = ldb8(qp + 16);

    const int rk0 = qslot * 16 + (lane >> 2);
    const int ck0 = (lane & 3) ^ ((rk0 >> 1) & 3);
    const unsigned short* gk0 = Kb
        + (((size_t)(km * NHD + h)) * NTOK + kseg * 864 + rk0) * HDIM + ck0 * 8;
    const int dv0 = qslot * 16 + (lane >> 2);
    const int cv0 = (lane & 3) ^ ((dv0 >> 1) & 3);   // FIXED: was ^(dv0&3)
    const unsigned short* gv0 = V2
        + ((size_t)(h * HDIM + dv0)) * NKEY + km * NTOK + kseg * 864 + cv0 * 8;

    const int fKV = (l31 >> 1) & 3;                  // FIXED: V now uses K's pattern
    const int kA0 = l31 * 32 + ((hi ^ fKV) << 3);
    const int kB0 = l31 * 32 + (((2 + hi) ^ fKV) << 3);
    const int vo0 = l31 * 32 + ((hi ^ fKV) << 3);
    const int vo1 = l31 * 32 + (((2 + hi) ^ fKV) << 3);

    f32x16 z;
    #pragma unroll
    for (int r = 0; r < 16; ++r) z[r] = 0.f;
    f32x16 o_acc = z, s_acc = z;
    bf16x8 onesv;
    #pragma unroll
    for (int j = 0; j < 8; ++j) onesv[j] = (__bf16)1.0f;

    #define STAGE(bb) do {                                      \
        glds16(gk0, &smAll[bb][ks][0][0] + qslot * 512);        \
        glds16(gv0, &smAll[bb][ks][1][0] + qslot * 512);        \
        gk0 += 1024; gv0 += 32;                                 \
    } while (0)

    STAGE(0);
    __syncthreads();

    int buf = 0;
    for (int t = 0; t < NT; ++t) {
        if (t + 1 < NT) STAGE(buf ^ 1);
        const unsigned short* Kl = &smAll[buf][ks][0][0];
        const unsigned short* Vl = &smAll[buf][ks][1][0];

        bf16x8 k0 = ldb8(Kl + kA0);
        bf16x8 k1 = ldb8(Kl + kB0);
        f32x16 c = __builtin_amdgcn_mfma_f32_32x32x16_bf16(k0, qf0, z, 0, 0, 0);
        c = __builtin_amdgcn_mfma_f32_32x32x16_bf16(k1, qf1, c, 0, 0, 0);

        float e[16];
        #pragma unroll
        for (int r = 0; r < 16; ++r) e[r] = EXP2(c[r]);
        bf16x8 pa0, pa1;
        #pragma unroll
        for (int j = 0; j < 8; ++j) { pa0[j] = (__bf16)e[j]; pa1[j] = (__bf16)e[8 + j]; }

        bf16x8 v0 = ldb8(Vl + vo0);
        bf16x8 v1 = ldb8(Vl + vo1);

        o_acc = __builtin_amdgcn_mfma_f32_32x32x16_bf16(pa0, v0, o_acc, 0, 0, 0);
        o_acc = __builtin_amdgcn_mfma_f32_32x32x16_bf16(pa1, v1, o_acc, 0, 0, 0);
        s_acc = __builtin_amdgcn_mfma_f32_32x32x16_bf16(pa0, onesv, s_acc, 0, 0, 0);
        s_acc = __builtin_amdgcn_mfma_f32_32x32x16_bf16(pa1, onesv, s_acc, 0, 0, 0);

        __syncthreads();
        buf ^= 1;
    }
    #undef STAGE

    float* accfL = (float*)&smAll[0][0][0][0];   // 64*33*4 = 8.4 KB (reuse)
    if (ks == 1) {
        #pragma unroll
        for (int r = 0; r < 16; ++r) {
            const int qrow = (r & 3) + 8 * (r >> 2) + 4 * hi;
            accfL[(qslot * 32 + qrow) * 33 + l31] = o_acc[r];
            if (l31 == 0) accfL[(qslot * 32 + qrow) * 33 + 32] = s_acc[r];
        }
    }
    __syncthreads();
    if (ks == 0) {
        #pragma unroll
        for (int r = 0; r < 16; ++r) {
            const int qrow = (r & 3) + 8 * (r >> 2) + 4 * hi;
            accfL[(qslot * 32 + qrow) * 33 + l31] += o_acc[r];
            if (l31 == 0) accfL[(qslot * 32 + qrow) * 33 + 32] += s_acc[r];
        }
    }
    __syncthreads();
    {
        const int q  = tid & 63;
        const int dq = tid >> 6;
        #pragma unroll
        for (int j = 0; j < 8; ++j) {
            const int d = dq * 8 + j;
            accT[((size_t)((p * 4 + h) * HDIM + d)) * NKEY + (size_t)qb * 64 + q]
                = accfL[q * 33 + d];
        }
        if (tid < 64)
            sR[((size_t)(p * 4 + h)) * NKEY + (size_t)qb * 64 + tid] = accfL[tid * 33 + 32];
    }
}

// ---------------------------------------------------------------------------
// Kernel 3: fused normalize + modality-sum + MFMA out-proj + BN + ReLU
// (R14/R15). 54 blocks × 512 thr.
// ---------------------------------------------------------------------------
__global__ __launch_bounds__(512) void normout_kernel(
    const float* __restrict__ accT, const float* __restrict__ sR,
    const float* __restrict__ Wout,
    const float* __restrict__ gamma, const float* __restrict__ beta,
    const float* __restrict__ mean,  const float* __restrict__ var,
    float* __restrict__ out)
{
    __shared__ __align__(16) unsigned short fT2[32][136];  // 8.7 KB
    __shared__ float rsL[4][4][32];                        // 2 KB

    const int tid = threadIdx.x;
    const int nb  = blockIdx.x * 32;

    // --- phase A: rsL[h][imq][n] = 1 / sum_pp sR ---
    {
        const int h = tid >> 7, imq = (tid >> 5) & 3, n = tid & 31;
        float s = 0.f;
        #pragma unroll
        for (int pp = 0; pp < 4; ++pp)
            s += sR[(size_t)(pp * 4 + h) * NKEY + (size_t)imq * NTOK + nb + n];
        rsL[h][imq][n] = 1.0f / s;
    }
    __syncthreads();

    // --- phase B: fusedT[n][c] bf16 (thread = 2c × 4n) ---
    {
        const int n4 = (tid & 7) * 4;        // n base
        const int c0 = (tid >> 3) * 2;       // c base (even, 0..126)
        const int h  = c0 >> 5;
        float acc4[2][4] = {};
        #pragma unroll
        for (int imq = 0; imq < 4; ++imq) {
            const size_t q = (size_t)imq * NTOK + nb + n4;
            float a[2][4] = {};
            #pragma unroll
            for (int pp = 0; pp < 4; ++pp) {
                #pragma unroll
                for (int cc = 0; cc < 2; ++cc) {
                    const int d = (c0 + cc) & 31;
                    float4 x = *reinterpret_cast<const float4*>(
                        accT + ((size_t)((pp * 4 + h) * HDIM + d)) * NKEY + q);
                    a[cc][0] += x.x; a[cc][1] += x.y; a[cc][2] += x.z; a[cc][3] += x.w;
                }
            }
            #pragma unroll
            for (int cc = 0; cc < 2; ++cc)
                #pragma unroll
                for (int nn = 0; nn < 4; ++nn)
                    acc4[cc][nn] = fmaf(a[cc][nn], rsL[h][imq][n4 + nn], acc4[cc][nn]);
        }
        #pragma unroll
        for (int nn = 0; nn < 4; ++nn) {
            ushort2 pk;
            pk.x = bfc(acc4[0][nn]); pk.y = bfc(acc4[1][nn]);
            *reinterpret_cast<ushort2*>(&fT2[n4 + nn][c0]) = pk;
        }
    }
    __syncthreads();

    // --- phase C: MFMA out-proj + BN + ReLU (waves 0-3) ---
    if (tid < 256) {
        const int lane = tid & 63;
        const int w    = tid >> 6;
        const int l31  = lane & 31;
        const int hi   = lane >> 5;
        const float* Arow = Wout + (size_t)(w * 32 + l31) * CH + hi * 8;
        f32x16 acc;
        #pragma unroll
        for (int r = 0; r < 16; ++r) acc[r] = 0.f;
        #pragma unroll
        for (int cc = 0; cc < 8; ++cc) {
            bf16x8 a = cvt8(Arow + cc * 16, 1.0f);
            bf16x8 b = ldb8(&fT2[l31][cc * 16 + hi * 8]);
            acc = __builtin_amdgcn_mfma_f32_32x32x16_bf16(a, b, acc, 0, 0, 0);
        }
        #pragma unroll
        for (int r = 0; r < 16; ++r) {
            const int orow = w * 32 + (r & 3) + 8 * (r >> 2) + 4 * hi;
            const float inv = gamma[orow] * rsqrtf(var[orow] + 1e-5f);
            const float sh  = fmaf(-mean[orow], inv, beta[orow]);
            out[(size_t)orow * NTOK + nb + l31] = fmaxf(fmaf(acc[r], inv, sh), 0.f);
        }
    }
}

// ---------------------------------------------------------------------------
extern "C" void kernel_launch(void* const* d_in, const int* in_sizes, int n_in,
                              void* d_out, int out_size, void* d_ws, size_t ws_size,
                              hipStream_t stream)
{
    const float* f0    = (const float*)d_in[0];
    const float* f1    = (const float*)d_in[1];
    const float* f2    = (const float*)d_in[2];
    const float* f3    = (const float*)d_in[3];
    const float* Wq    = (const float*)d_in[4];
    const float* Wk    = (const float*)d_in[5];
    const float* Wv    = (const float*)d_in[6];
    const float* Wout  = (const float*)d_in[7];
    const float* gamma = (const float*)d_in[8];
    const float* beta  = (const float*)d_in[9];
    const float* mean  = (const float*)d_in[10];
    const float* var   = (const float*)d_in[11];
    float* out = (float*)d_out;

    const size_t QKV = (size_t)MODS * NHD * NTOK * HDIM;   // 884736 elems
    unsigned short* Qb  = (unsigned short*)d_ws;
    unsigned short* Kb  = Qb + QKV;
    unsigned short* V2  = Kb + QKV;
    float* accT = (float*)(V2 + QKV);           // [512 rows][6912 q] f32
    float* sR   = accT + (size_t)512 * NKEY;    // [16][6912] f32

    proj_kernel<<<648, 256, 0, stream>>>(f0, f1, f2, f3, Wq, Wk, Wv, Qb, Kb, V2);
    attn_kernel<<<1728, 256, 0, stream>>>(Qb, Kb, V2, accT, sR);
    normout_kernel<<<54, 512, 0, stream>>>(
        accT, sR, Wout, gamma, beta, mean, var, out);
}